// Round 4
// baseline (388.525 us; speedup 1.0000x reference)
//
#include <hip/hip_runtime.h>
#include <hip/hip_bf16.h>

// MultiheadAttention with relative position bias, MI355X gfx950.
// L=1024, B=16, E=512, H=8, d=64. Inputs/output fp32; ws intermediates fp16.
//
// Stage 0: rpe_expand   -- R11: materialize EB[h][qg][jt][lane][32] f16 = tab[h][idx[q][k]]
//                          in MFMA D-fragment order (batch-independent: computed ONCE,
//                          was re-gathered 16x inside attn = 134M gathers -> 8.4M)
// Stage 1: qkv_kernel   -- MFMA in_proj GEMMs -> Q,K,V fp16, (B,H,L,64), q pre-scaled 1/8
//                          R10: f16 reg-staged LDS, raw-barrier pipeline
// Stage 2: transpose_v  -- V (B,H,L,64) -> Vt (B,H,64,L) for MFMA B-operand
// Stage 3: attn_kernel  -- MFMA flash attention, bias via coalesced EB loads
//                          (no tab LDS / no idx loads -> 36.9KB LDS, 4 blocks/CU)
// Stage 4: out_kernel   -- MFMA out_proj GEMM -> fp32 output (L,B,E), R10 pipeline
//
// ws (fp16 elems): Q @0, K @8M, Vt @16M, Vtmp/CTX @24M (aliased), EB @32M (16MB).
//
// MFMA f16 16x16x32 layouts (verified end-to-end in this problem, round 4):
//   A[m=lane&15][k=quad*8+j], B[k=quad*8+j][n=lane&15], D[row=quad*4+reg][col=lane&15]

#define L_SEQ 1024
#define B_N   16
#define E_DIM 512
#define H_N   8
#define NREL  2047

typedef _Float16 f16;
using half4   = __attribute__((ext_vector_type(4))) _Float16;
using half8   = __attribute__((ext_vector_type(8))) _Float16;
using floatx4 = __attribute__((ext_vector_type(4))) float;

// lgkmcnt(0) drain (ds_write visibility) + raw barrier, pinned against code motion.
// Does NOT drain vmcnt -> global loads stay in flight across the barrier.
#define LGKM_BARRIER() do {                                   \
    asm volatile("s_waitcnt lgkmcnt(0)" ::: "memory");        \
    __builtin_amdgcn_sched_barrier(0);                        \
    __builtin_amdgcn_s_barrier();                             \
    __builtin_amdgcn_sched_barrier(0);                        \
} while (0)

__device__ __forceinline__ half4 cvt4(const float4 a) {
    half4 h;
    h[0] = (f16)a.x; h[1] = (f16)a.y; h[2] = (f16)a.z; h[3] = (f16)a.w;
    return h;
}

// ---------------------------------------------------------------------------
// Stage 0: RPE bias expansion. grid (32 qg, 16 jt), block 256 (4 waves x 2 heads).
// EB[h][qg][jt][lane][s*16+nt*4+r] = tab[h][ idx[qg*32+s*16+quad*4+r][jt*64+nt*16+c] ]
// -> attn lane reads its 32 per-iter bias values as 4 contiguous uint4.
// ---------------------------------------------------------------------------
__global__ __launch_bounds__(256) void rpe_expand(
    const int* __restrict__ RPE, const float* __restrict__ Tab, f16* __restrict__ EB)
{
    const int qg = blockIdx.x;          // 0..31
    const int jt = blockIdx.y;          // 0..15
    __shared__ float tabs[H_N * NREL];  // 65504 B
    const int tid = threadIdx.x;
    for (int i = tid; i < H_N * NREL; i += 256) tabs[i] = Tab[i];

    const int w = tid >> 6, lane = tid & 63;
    const int quad = lane >> 4, c = lane & 15;

    // idx gathers (once; shared across all 8 heads and all 16 batches)
    const int* rp = RPE + (size_t)(qg * 32 + quad * 4) * 1024 + jt * 64 + c;
    int id[2][4][4];
#pragma unroll
    for (int s = 0; s < 2; ++s)
#pragma unroll
        for (int r = 0; r < 4; ++r)
#pragma unroll
            for (int nt = 0; nt < 4; ++nt)
                id[s][r][nt] = rp[(size_t)(s * 16 + r) * 1024 + nt * 16];

    __syncthreads();                    // tabs ready

#pragma unroll
    for (int hh = 0; hh < 2; ++hh) {
        const int h = w * 2 + hh;
        union { f16 v[32]; uint4 u[4]; } o;
#pragma unroll
        for (int s = 0; s < 2; ++s)
#pragma unroll
            for (int nt = 0; nt < 4; ++nt)
#pragma unroll
                for (int r = 0; r < 4; ++r)
                    o.v[s * 16 + nt * 4 + r] = (f16)tabs[h * NREL + id[s][r][nt]];

        f16* dst = EB + ((((size_t)h * 32 + qg) * 16 + jt) << 11) + lane * 32;
#pragma unroll
        for (int i = 0; i < 4; ++i)
            *reinterpret_cast<uint4*>(dst + i * 8) = o.u[i];
    }
}

// ---------------------------------------------------------------------------
// Stage 1: in_proj MFMA GEMM. 1536 blocks, XCD-swizzled so the 4 f-tile
// blocks sharing an X row-slice land on one XCD (same L2).
// Pipeline per iter: compute(buf[t&1]) ; cvt+write(t+1) ; issue loads(t+2) ;
// lgkmcnt(0)+s_barrier.  Loads issued at iter t are consumed at iter t+1's
// write phase -> ~1 barrier + 1 compute phase of latency cover.
// ---------------------------------------------------------------------------
__global__ __launch_bounds__(256) void qkv_kernel(
    const float* __restrict__ Xq, const float* __restrict__ Xk, const float* __restrict__ Xv,
    const float* __restrict__ W, const float* __restrict__ Bias,
    f16* __restrict__ Qo, f16* __restrict__ Ko, f16* __restrict__ Vo)
{
    // swizzle: xcd = flat&7; 48 groups (m,proj) per XCD; 4 f-tiles per group
    const int flat = blockIdx.x;
    const int xcd  = flat & 7;
    const int slot = flat >> 3;            // 0..191
    const int g    = xcd * 48 + (slot >> 2);   // 0..383 = proj*128 + mtile
    const int f0   = (slot & 3) << 7;
    const int proj = g >> 7;               // 0=q 1=k 2=v
    const int n0   = (g & 127) << 7;

    const float* X  = (proj == 0) ? Xq : (proj == 1) ? Xk : Xv;
    const float* Wp = W + (size_t)(proj << 9) * E_DIM;

    // f16 tiles, padded rows (40 f16 = 80 B -> bank spread), double-buffered. 40 KB.
    __shared__ __align__(16) f16 As[2][128][40];
    __shared__ __align__(16) f16 Bs[2][128][40];

    const int tid  = threadIdx.x;
    const int w    = tid >> 6;
    const int lane = tid & 63;
    const int quad = lane >> 4, c = lane & 15;
    const int wm = (w >> 1) << 6, wn = (w & 1) << 6;

    // staging: wave w covers rows [w*32, w*32+32); instr i: row = w*32+i*8+(lane>>3),
    // cols (lane&7)*4 .. +3 (fp32) -> 8 rows x 128 B contiguous segments per instr.
    const int srow = (w << 5) + (lane >> 3);     // + i*8
    const int scol = (lane & 7) << 2;
    const float* Xg = X  + (size_t)(n0 + srow) * E_DIM + scol;
    const float* Wg = Wp + (size_t)(f0 + srow) * E_DIM + scol;

    float4 lx[4], lw[4];
    auto load_tile = [&](int kk) {
#pragma unroll
        for (int i = 0; i < 4; ++i)
            lx[i] = *reinterpret_cast<const float4*>(Xg + (size_t)(i * 8) * E_DIM + kk);
#pragma unroll
        for (int i = 0; i < 4; ++i)
            lw[i] = *reinterpret_cast<const float4*>(Wg + (size_t)(i * 8) * E_DIM + kk);
    };
    auto write_tile = [&](int buf) {
#pragma unroll
        for (int i = 0; i < 4; ++i)
            *reinterpret_cast<half4*>(&As[buf][srow + i * 8][scol]) = cvt4(lx[i]);
#pragma unroll
        for (int i = 0; i < 4; ++i)
            *reinterpret_cast<half4*>(&Bs[buf][srow + i * 8][scol]) = cvt4(lw[i]);
    };

    floatx4 acc[4][4] = {};

    // prologue: tile0 staged+visible; tile1 loads in flight
    load_tile(0);
    write_tile(0);
    load_tile(32);
    LGKM_BARRIER();

    for (int t = 0; t < 16; ++t) {
        const int cur = t & 1;

        half8 a[4], bfr[4];
#pragma unroll
        for (int mt = 0; mt < 4; ++mt)
            a[mt] = *reinterpret_cast<const half8*>(&As[cur][wm + mt * 16 + c][quad * 8]);
#pragma unroll
        for (int nt = 0; nt < 4; ++nt)
            bfr[nt] = *reinterpret_cast<const half8*>(&Bs[cur][wn + nt * 16 + c][quad * 8]);
#pragma unroll
        for (int mt = 0; mt < 4; ++mt)
#pragma unroll
            for (int nt = 0; nt < 4; ++nt)
                acc[mt][nt] = __builtin_amdgcn_mfma_f32_16x16x32_f16(a[mt], bfr[nt], acc[mt][nt], 0, 0, 0);

        if (t < 15) {
            write_tile(cur ^ 1);               // cvt consumes loads(t+1); auto vmcnt wait
            if (t < 14) load_tile((t + 2) * 32);  // regs free -> issue next, flies over barrier
        }
        LGKM_BARRIER();
    }

    f16* Dst = (proj == 0) ? Qo : (proj == 1) ? Ko : Vo;
    const float scale = (proj == 0) ? 0.125f : 1.0f;

#pragma unroll
    for (int nt = 0; nt < 4; ++nt) {
        const int fl = f0 + wn + nt * 16 + c;
        const float bj = Bias[(proj << 9) + fl];
        const int h = fl >> 6, d = fl & 63;
#pragma unroll
        for (int mt = 0; mt < 4; ++mt) {
#pragma unroll
            for (int r = 0; r < 4; ++r) {
                const int n = n0 + wm + mt * 16 + quad * 4 + r;
                const int l = n >> 4, b = n & 15;
                Dst[((((size_t)b * H_N + h) * L_SEQ + l) << 6) + d] =
                    (f16)((acc[mt][nt][r] + bj) * scale);
            }
        }
    }
}

// ---------------------------------------------------------------------------
// Stage 2: V (b,h)[l][d] -> Vt (b,h)[d][l]. grid (16, 128), block 256.
// ---------------------------------------------------------------------------
__global__ __launch_bounds__(256) void transpose_v(
    const f16* __restrict__ V, f16* __restrict__ Vt)
{
    const int l0 = blockIdx.x << 6;
    const size_t base = (size_t)blockIdx.y << 16;
    __shared__ __align__(16) f16 T[64][72];
    const int tid = threadIdx.x;
    const int r = tid >> 2, co = (tid & 3) << 4;

    const uint4 a0 = *reinterpret_cast<const uint4*>(V + base + (size_t)(l0 + r) * 64 + co);
    const uint4 a1 = *reinterpret_cast<const uint4*>(V + base + (size_t)(l0 + r) * 64 + co + 8);
    *reinterpret_cast<uint4*>(&T[r][co])     = a0;
    *reinterpret_cast<uint4*>(&T[r][co + 8]) = a1;
    __syncthreads();

    union { f16 h[16]; uint4 u[2]; } pk;
#pragma unroll
    for (int j = 0; j < 16; ++j) pk.h[j] = T[co + j][r];
    *reinterpret_cast<uint4*>(Vt + base + (size_t)r * 1024 + l0 + co)     = pk.u[0];
    *reinterpret_cast<uint4*>(Vt + base + (size_t)r * 1024 + l0 + co + 8) = pk.u[1];
}

// ---------------------------------------------------------------------------
// Stage 3: MFMA flash attention, fixed-max softmax. 1024 blocks, block 256.
// R11: bias via EB fragment-order loads (4 uint4/lane/iter, prefetched); no tab
// LDS, no idx loads -> LDS 36.9KB (4 blocks/CU), ~32 fewer VGPRs.
// XCD swizzle: the 8 q-tile blocks of each (b,h) share K/V through one L2.
// ---------------------------------------------------------------------------
__global__ __launch_bounds__(256, 4) void attn_kernel(
    const f16* __restrict__ Q, const f16* __restrict__ K, const f16* __restrict__ Vt,
    const f16* __restrict__ EB, f16* __restrict__ CTX)
{
    // swizzle: xcd = flat&7; bh = (slot>>3)*8 + xcd; q-tile = slot&7
    const int flat = blockIdx.x;
    const int xcd  = flat & 7;
    const int slot = flat >> 3;            // 0..127
    const int q0   = (slot & 7) << 7;
    const int bh   = ((slot >> 3) << 3) + xcd;
    const int b = bh >> 3, h = bh & 7;

    const int tid  = threadIdx.x;
    const int w    = tid >> 6;
    const int lane = tid & 63;
    const int quad = lane >> 4, c = lane & 15;

    __shared__ __align__(16) f16 Ks[64][72];
    __shared__ __align__(16) f16 Vts[64][72];
    __shared__ __align__(16) f16 Pw[4][32][72];

    const size_t base = (size_t)bh << 16;

    const int qg0 = q0 + (w << 5);
    half8 Aq[2][2];
#pragma unroll
    for (int s = 0; s < 2; ++s) {
        const f16* qp = Q + base + (size_t)(qg0 + s * 16 + c) * 64 + quad * 8;
        Aq[s][0] = *reinterpret_cast<const half8*>(qp);
        Aq[s][1] = *reinterpret_cast<const half8*>(qp + 32);
    }

    floatx4 o[2][4] = {};
    float l_part[2][4] = {};

    // EB slab for (h, qg = q0/32 + w): 16 iters x 2048 f16, lane-contiguous
    const f16* ebp = EB + ((((size_t)h * 32 + (q0 >> 5) + w) * 16) << 11) + (size_t)lane * 32;

    const int sr = tid >> 2, so = (tid & 3) << 4;
    const f16* kbase = K  + base + (size_t)sr * 64 + so;
    const f16* vbase = Vt + base + (size_t)sr * 1024 + so;

    uint4 pk0 = *reinterpret_cast<const uint4*>(kbase);
    uint4 pk1 = *reinterpret_cast<const uint4*>(kbase + 8);
    uint4 pv0 = *reinterpret_cast<const uint4*>(vbase);
    uint4 pv1 = *reinterpret_cast<const uint4*>(vbase + 8);
    uint4 pe[4];
#pragma unroll
    for (int i = 0; i < 4; ++i)
        pe[i] = *reinterpret_cast<const uint4*>(ebp + i * 8);

    for (int j0 = 0; j0 < L_SEQ; j0 += 64) {
        __syncthreads();
        *reinterpret_cast<uint4*>(&Ks[sr][so])      = pk0;
        *reinterpret_cast<uint4*>(&Ks[sr][so + 8])  = pk1;
        *reinterpret_cast<uint4*>(&Vts[sr][so])     = pv0;
        *reinterpret_cast<uint4*>(&Vts[sr][so + 8]) = pv1;
        __syncthreads();

        union { uint4 u[4]; half8 h[4]; } eb;
#pragma unroll
        for (int i = 0; i < 4; ++i) eb.u[i] = pe[i];

        if (j0 + 64 < L_SEQ) {
            const f16* kn = kbase + (size_t)(j0 + 64) * 64;
            const f16* vn = vbase + (j0 + 64);
            pk0 = *reinterpret_cast<const uint4*>(kn);
            pk1 = *reinterpret_cast<const uint4*>(kn + 8);
            pv0 = *reinterpret_cast<const uint4*>(vn);
            pv1 = *reinterpret_cast<const uint4*>(vn + 8);
            const f16* en = ebp + (size_t)(j0 / 64 + 1) * 2048;
#pragma unroll
            for (int i = 0; i < 4; ++i)
                pe[i] = *reinterpret_cast<const uint4*>(en + i * 8);
        }

        floatx4 sc[2][4];
#pragma unroll
        for (int nt = 0; nt < 4; ++nt) {
            const half8 b0 = *reinterpret_cast<const half8*>(&Ks[nt * 16 + c][quad * 8]);
            const half8 b1 = *reinterpret_cast<const half8*>(&Ks[nt * 16 + c][32 + quad * 8]);
            floatx4 t0 = {}, t1 = {};
            t0 = __builtin_amdgcn_mfma_f32_16x16x32_f16(Aq[0][0], b0, t0, 0, 0, 0);
            t0 = __builtin_amdgcn_mfma_f32_16x16x32_f16(Aq[0][1], b1, t0, 0, 0, 0);
            t1 = __builtin_amdgcn_mfma_f32_16x16x32_f16(Aq[1][0], b0, t1, 0, 0, 0);
            t1 = __builtin_amdgcn_mfma_f32_16x16x32_f16(Aq[1][1], b1, t1, 0, 0, 0);
            sc[0][nt] = t0; sc[1][nt] = t1;
        }

        // EB fragment order: v[s*16 + nt*4 + r] -> chunk s*2+(nt>>1), elem (nt&1)*4+r
#pragma unroll
        for (int s = 0; s < 2; ++s)
#pragma unroll
            for (int r = 0; r < 4; ++r) {
                float rs = 0.0f;
#pragma unroll
                for (int nt = 0; nt < 4; ++nt) {
                    const float bias = (float)eb.h[s * 2 + (nt >> 1)][(nt & 1) * 4 + r];
                    const float p = __expf(sc[s][nt][r] + bias);
                    rs += p;
                    Pw[w][s * 16 + quad * 4 + r][nt * 16 + c] = (f16)p;
                }
                l_part[s][r] += rs;
            }

        half8 vb[4][2];
#pragma unroll
        for (int nt = 0; nt < 4; ++nt) {
            vb[nt][0] = *reinterpret_cast<const half8*>(&Vts[nt * 16 + c][quad * 8]);
            vb[nt][1] = *reinterpret_cast<const half8*>(&Vts[nt * 16 + c][32 + quad * 8]);
        }
#pragma unroll
        for (int s = 0; s < 2; ++s) {
            const half8 Ap0 = *reinterpret_cast<const half8*>(&Pw[w][s * 16 + c][quad * 8]);
            const half8 Ap1 = *reinterpret_cast<const half8*>(&Pw[w][s * 16 + c][32 + quad * 8]);
#pragma unroll
            for (int nt = 0; nt < 4; ++nt) {
                o[s][nt] = __builtin_amdgcn_mfma_f32_16x16x32_f16(Ap0, vb[nt][0], o[s][nt], 0, 0, 0);
                o[s][nt] = __builtin_amdgcn_mfma_f32_16x16x32_f16(Ap1, vb[nt][1], o[s][nt], 0, 0, 0);
            }
        }
    }

#pragma unroll
    for (int s = 0; s < 2; ++s)
#pragma unroll
        for (int r = 0; r < 4; ++r) {
            float l = l_part[s][r];
            l += __shfl_xor(l, 1); l += __shfl_xor(l, 2);
            l += __shfl_xor(l, 4); l += __shfl_xor(l, 8);
            const float inv = 1.0f / l;
            const int lrow = qg0 + s * 16 + quad * 4 + r;
            f16* dp = CTX + ((size_t)(lrow * 16 + b)) * 512 + h * 64;
#pragma unroll
            for (int nt = 0; nt < 4; ++nt)
                dp[nt * 16 + c] = (f16)(o[s][nt][r] * inv);
        }
}

// ---------------------------------------------------------------------------
// Stage 4: out_proj MFMA GEMM. 512 blocks, XCD-swizzled, R10 pipeline.
// A = CTX (f16 pass-through regs); B = W (fp32 -> cvt at write).
// ---------------------------------------------------------------------------
__global__ __launch_bounds__(256) void out_kernel(
    const f16* __restrict__ X, const float* __restrict__ W, const float* __restrict__ Bias,
    float* __restrict__ Out)
{
    // swizzle: 16 m-groups per XCD, 4 f-tiles per group on same XCD
    const int flat = blockIdx.x;
    const int xcd  = flat & 7;
    const int slot = flat >> 3;            // 0..63
    const int m    = xcd * 16 + (slot >> 2);   // 0..127
    const int f0   = (slot & 3) << 7;
    const int n0   = m << 7;

    __shared__ __align__(16) f16 As[2][128][40];
    __shared__ __align__(16) f16 Bs[2][128][40];

    const int tid  = threadIdx.x;
    const int w    = tid >> 6;
    const int lane = tid & 63;
    const int quad = lane >> 4, c = lane & 15;
    const int wm = (w >> 1) << 6, wn = (w & 1) << 6;

    // A staging (f16): instr i: row = w*32 + i*16 + (lane>>2), col = (lane&3)*8
    const int arow = (w << 5) + (lane >> 2);     // + i*16
    const int acol = (lane & 3) << 3;
    const f16* Xg = X + (size_t)(n0 + arow) * E_DIM + acol;

    // B staging (fp32): as qkv
    const int srow = (w << 5) + (lane >> 3);     // + i*8
    const int scol = (lane & 7) << 2;
    const float* Wg = W + (size_t)(f0 + srow) * E_DIM + scol;

    uint4  la[2];
    float4 lw[4];
    auto load_tile = [&](int kk) {
#pragma unroll
        for (int i = 0; i < 2; ++i)
            la[i] = *reinterpret_cast<const uint4*>(Xg + (size_t)(i * 16) * E_DIM + kk);
#pragma unroll
        for (int i = 0; i < 4; ++i)
            lw[i] = *reinterpret_cast<const float4*>(Wg + (size_t)(i * 8) * E_DIM + kk);
    };
    auto write_tile = [&](int buf) {
#pragma unroll
        for (int i = 0; i < 2; ++i)
            *reinterpret_cast<uint4*>(&As[buf][arow + i * 16][acol]) = la[i];
#pragma unroll
        for (int i = 0; i < 4; ++i)
            *reinterpret_cast<half4*>(&Bs[buf][srow + i * 8][scol]) = cvt4(lw[i]);
    };

    floatx4 acc[4][4] = {};

    load_tile(0);
    write_tile(0);
    load_tile(32);
    LGKM_BARRIER();

    for (int t = 0; t < 16; ++t) {
        const int cur = t & 1;

        half8 a[4], bfr[4];
#pragma unroll
        for (int mt = 0; mt < 4; ++mt)
            a[mt] = *reinterpret_cast<const half8*>(&As[cur][wm + mt * 16 + c][quad * 8]);
#pragma unroll
        for (int nt = 0; nt < 4; ++nt)
            bfr[nt] = *reinterpret_cast<const half8*>(&Bs[cur][wn + nt * 16 + c][quad * 8]);
#pragma unroll
        for (int mt = 0; mt < 4; ++mt)
#pragma unroll
            for (int nt = 0; nt < 4; ++nt)
                acc[mt][nt] = __builtin_amdgcn_mfma_f32_16x16x32_f16(a[mt], bfr[nt], acc[mt][nt], 0, 0, 0);

        if (t < 15) {
            write_tile(cur ^ 1);
            if (t < 14) load_tile((t + 2) * 32);
        }
        LGKM_BARRIER();
    }

#pragma unroll
    for (int nt = 0; nt < 4; ++nt) {
        const int f = f0 + wn + nt * 16 + c;
        const float bj = Bias[f];
#pragma unroll
        for (int mt = 0; mt < 4; ++mt) {
#pragma unroll
            for (int r = 0; r < 4; ++r) {
                const int n = n0 + wm + mt * 16 + quad * 4 + r;
                Out[(size_t)n * E_DIM + f] = acc[mt][nt][r] + bj;
            }
        }
    }
}

// ---------------------------------------------------------------------------
extern "C" void kernel_launch(void* const* d_in, const int* in_sizes, int n_in,
                              void* d_out, int out_size, void* d_ws, size_t ws_size,
                              hipStream_t stream) {
    const float* q_in = (const float*)d_in[0];
    const float* k_in = (const float*)d_in[1];
    const float* v_in = (const float*)d_in[2];
    const float* ipw  = (const float*)d_in[3];
    const float* ipb  = (const float*)d_in[4];
    const float* opw  = (const float*)d_in[5];
    const float* opb  = (const float*)d_in[6];
    const float* tab  = (const float*)d_in[7];
    const int*   rpe  = (const int*)d_in[8];
    float* out = (float*)d_out;

    f16* ws   = (f16*)d_ws;
    f16* Q    = ws;
    f16* K    = ws + 8388608;
    f16* Vt   = ws + 16777216;
    f16* Vtmp = ws + 25165824;
    f16* CTX  = ws + 25165824;
    f16* EB   = ws + 33554432;   // 16 MB fragment-order bias table

    rpe_expand<<<dim3(32, 16), 256, 0, stream>>>(rpe, tab, EB);
    qkv_kernel<<<dim3(1536), 256, 0, stream>>>(q_in, k_in, v_in, ipw, ipb, Q, K, Vtmp);
    transpose_v<<<dim3(16, 128), 256, 0, stream>>>(Vtmp, Vt);
    attn_kernel<<<dim3(1024), 256, 0, stream>>>(Q, K, Vt, EB, CTX);
    out_kernel<<<dim3(512), 256, 0, stream>>>(CTX, opw, opb, out);
}

// Round 5
// 332.684 us; speedup vs baseline: 1.1679x; 1.1679x over previous
//
#include <hip/hip_runtime.h>
#include <hip/hip_bf16.h>

// MultiheadAttention with relative position bias, MI355X gfx950.
// L=1024, B=16, E=512, H=8, d=64. Inputs/output fp32; ws intermediates fp16.
//
// Stage 1: qkv_kernel   -- MFMA in_proj GEMMs -> Q,K,V fp16, (B,H,L,64),
//                          q pre-scaled 1/8*log2e (R12: exp2 base-change folding)
//                          R10: f16 reg-staged LDS, raw-barrier pipeline
// Stage 2: transpose_v  -- V (B,H,L,64) -> Vt (B,H,64,L) for MFMA B-operand
// Stage 3: attn_kernel  -- MFMA flash attention w/ RPE bias -> CTX fp16 (L,B,E)
//                          R12: R10 staged body (proven 92us; EB streaming of R11
//                          cost 650MB HBM traffic -> reverted), + exp2f softmax
//                          (tab pre-scaled by log2e) + idx prefetch 1 j-tile ahead
// Stage 4: out_kernel   -- MFMA out_proj GEMM -> fp32 output (L,B,E), R10 pipeline
//
// ws (fp16 elems): Q @0, K @8M, Vt @16M, Vtmp/CTX @24M (aliased, disjoint lifetimes).
//
// MFMA f16 16x16x32 layouts (verified end-to-end in this problem, round 4):
//   A[m=lane&15][k=quad*8+j], B[k=quad*8+j][n=lane&15], D[row=quad*4+reg][col=lane&15]

#define L_SEQ 1024
#define B_N   16
#define E_DIM 512
#define H_N   8
#define NREL  2047
#define LOG2E 1.44269504f

typedef _Float16 f16;
using half4   = __attribute__((ext_vector_type(4))) _Float16;
using half8   = __attribute__((ext_vector_type(8))) _Float16;
using floatx4 = __attribute__((ext_vector_type(4))) float;

// lgkmcnt(0) drain (ds_write visibility) + raw barrier, pinned against code motion.
// Does NOT drain vmcnt -> global loads stay in flight across the barrier.
#define LGKM_BARRIER() do {                                   \
    asm volatile("s_waitcnt lgkmcnt(0)" ::: "memory");        \
    __builtin_amdgcn_sched_barrier(0);                        \
    __builtin_amdgcn_s_barrier();                             \
    __builtin_amdgcn_sched_barrier(0);                        \
} while (0)

__device__ __forceinline__ half4 cvt4(const float4 a) {
    half4 h;
    h[0] = (f16)a.x; h[1] = (f16)a.y; h[2] = (f16)a.z; h[3] = (f16)a.w;
    return h;
}

// ---------------------------------------------------------------------------
// Stage 1: in_proj MFMA GEMM. 1536 blocks, XCD-swizzled so the 4 f-tile
// blocks sharing an X row-slice land on one XCD (same L2).
// Pipeline per iter: compute(buf[t&1]) ; cvt+write(t+1) ; issue loads(t+2) ;
// lgkmcnt(0)+s_barrier.  Loads issued at iter t are consumed at iter t+1's
// write phase -> ~1 barrier + 1 compute phase of latency cover.
// ---------------------------------------------------------------------------
__global__ __launch_bounds__(256) void qkv_kernel(
    const float* __restrict__ Xq, const float* __restrict__ Xk, const float* __restrict__ Xv,
    const float* __restrict__ W, const float* __restrict__ Bias,
    f16* __restrict__ Qo, f16* __restrict__ Ko, f16* __restrict__ Vo)
{
    // swizzle: xcd = flat&7; 48 groups (m,proj) per XCD; 4 f-tiles per group
    const int flat = blockIdx.x;
    const int xcd  = flat & 7;
    const int slot = flat >> 3;            // 0..191
    const int g    = xcd * 48 + (slot >> 2);   // 0..383 = proj*128 + mtile
    const int f0   = (slot & 3) << 7;
    const int proj = g >> 7;               // 0=q 1=k 2=v
    const int n0   = (g & 127) << 7;

    const float* X  = (proj == 0) ? Xq : (proj == 1) ? Xk : Xv;
    const float* Wp = W + (size_t)(proj << 9) * E_DIM;

    // f16 tiles, padded rows (40 f16 = 80 B -> bank spread), double-buffered. 40 KB.
    __shared__ __align__(16) f16 As[2][128][40];
    __shared__ __align__(16) f16 Bs[2][128][40];

    const int tid  = threadIdx.x;
    const int w    = tid >> 6;
    const int lane = tid & 63;
    const int quad = lane >> 4, c = lane & 15;
    const int wm = (w >> 1) << 6, wn = (w & 1) << 6;

    // staging: wave w covers rows [w*32, w*32+32); instr i: row = w*32+i*8+(lane>>3),
    // cols (lane&7)*4 .. +3 (fp32) -> 8 rows x 128 B contiguous segments per instr.
    const int srow = (w << 5) + (lane >> 3);     // + i*8
    const int scol = (lane & 7) << 2;
    const float* Xg = X  + (size_t)(n0 + srow) * E_DIM + scol;
    const float* Wg = Wp + (size_t)(f0 + srow) * E_DIM + scol;

    float4 lx[4], lw[4];
    auto load_tile = [&](int kk) {
#pragma unroll
        for (int i = 0; i < 4; ++i)
            lx[i] = *reinterpret_cast<const float4*>(Xg + (size_t)(i * 8) * E_DIM + kk);
#pragma unroll
        for (int i = 0; i < 4; ++i)
            lw[i] = *reinterpret_cast<const float4*>(Wg + (size_t)(i * 8) * E_DIM + kk);
    };
    auto write_tile = [&](int buf) {
#pragma unroll
        for (int i = 0; i < 4; ++i)
            *reinterpret_cast<half4*>(&As[buf][srow + i * 8][scol]) = cvt4(lx[i]);
#pragma unroll
        for (int i = 0; i < 4; ++i)
            *reinterpret_cast<half4*>(&Bs[buf][srow + i * 8][scol]) = cvt4(lw[i]);
    };

    floatx4 acc[4][4] = {};

    // prologue: tile0 staged+visible; tile1 loads in flight
    load_tile(0);
    write_tile(0);
    load_tile(32);
    LGKM_BARRIER();

    for (int t = 0; t < 16; ++t) {
        const int cur = t & 1;

        half8 a[4], bfr[4];
#pragma unroll
        for (int mt = 0; mt < 4; ++mt)
            a[mt] = *reinterpret_cast<const half8*>(&As[cur][wm + mt * 16 + c][quad * 8]);
#pragma unroll
        for (int nt = 0; nt < 4; ++nt)
            bfr[nt] = *reinterpret_cast<const half8*>(&Bs[cur][wn + nt * 16 + c][quad * 8]);
#pragma unroll
        for (int mt = 0; mt < 4; ++mt)
#pragma unroll
            for (int nt = 0; nt < 4; ++nt)
                acc[mt][nt] = __builtin_amdgcn_mfma_f32_16x16x32_f16(a[mt], bfr[nt], acc[mt][nt], 0, 0, 0);

        if (t < 15) {
            write_tile(cur ^ 1);               // cvt consumes loads(t+1); auto vmcnt wait
            if (t < 14) load_tile((t + 2) * 32);  // regs free -> issue next, flies over barrier
        }
        LGKM_BARRIER();
    }

    f16* Dst = (proj == 0) ? Qo : (proj == 1) ? Ko : Vo;
    // q pre-scale folds softmax base-change: exp(x) = exp2(x*log2e)
    const float scale = (proj == 0) ? (0.125f * LOG2E) : 1.0f;

#pragma unroll
    for (int nt = 0; nt < 4; ++nt) {
        const int fl = f0 + wn + nt * 16 + c;
        const float bj = Bias[(proj << 9) + fl];
        const int h = fl >> 6, d = fl & 63;
#pragma unroll
        for (int mt = 0; mt < 4; ++mt) {
#pragma unroll
            for (int r = 0; r < 4; ++r) {
                const int n = n0 + wm + mt * 16 + quad * 4 + r;
                const int l = n >> 4, b = n & 15;
                Dst[((((size_t)b * H_N + h) * L_SEQ + l) << 6) + d] =
                    (f16)((acc[mt][nt][r] + bj) * scale);
            }
        }
    }
}

// ---------------------------------------------------------------------------
// Stage 2: V (b,h)[l][d] -> Vt (b,h)[d][l]. grid (16, 128), block 256.
// ---------------------------------------------------------------------------
__global__ __launch_bounds__(256) void transpose_v(
    const f16* __restrict__ V, f16* __restrict__ Vt)
{
    const int l0 = blockIdx.x << 6;
    const size_t base = (size_t)blockIdx.y << 16;
    __shared__ __align__(16) f16 T[64][72];
    const int tid = threadIdx.x;
    const int r = tid >> 2, co = (tid & 3) << 4;

    const uint4 a0 = *reinterpret_cast<const uint4*>(V + base + (size_t)(l0 + r) * 64 + co);
    const uint4 a1 = *reinterpret_cast<const uint4*>(V + base + (size_t)(l0 + r) * 64 + co + 8);
    *reinterpret_cast<uint4*>(&T[r][co])     = a0;
    *reinterpret_cast<uint4*>(&T[r][co + 8]) = a1;
    __syncthreads();

    union { f16 h[16]; uint4 u[2]; } pk;
#pragma unroll
    for (int j = 0; j < 16; ++j) pk.h[j] = T[co + j][r];
    *reinterpret_cast<uint4*>(Vt + base + (size_t)r * 1024 + l0 + co)     = pk.u[0];
    *reinterpret_cast<uint4*>(Vt + base + (size_t)r * 1024 + l0 + co + 8) = pk.u[1];
}

// ---------------------------------------------------------------------------
// Stage 3: MFMA flash attention, fixed-max softmax. 1024 blocks, block 256.
// R12: R10 staged body + exp2f (tab pre-scaled log2e; Q pre-scaled in qkv) +
// idx loads for j0+64 issued after the exp section (covered by PV + barriers +
// staging + QK^T instead of being exposed after the staging barrier).
// XCD swizzle: the 8 q-tile blocks of each (b,h) share K/V through one L2.
// ---------------------------------------------------------------------------
__global__ __launch_bounds__(256, 3) void attn_kernel(
    const f16* __restrict__ Q, const f16* __restrict__ K, const f16* __restrict__ Vt,
    const int* __restrict__ RPE, const float* __restrict__ Tab, f16* __restrict__ CTX)
{
    // swizzle: xcd = flat&7; bh = (slot>>3)*8 + xcd; q-tile = slot&7
    const int flat = blockIdx.x;
    const int xcd  = flat & 7;
    const int slot = flat >> 3;            // 0..127
    const int q0   = (slot & 7) << 7;
    const int bh   = ((slot >> 3) << 3) + xcd;
    const int b = bh >> 3, h = bh & 7;

    const int tid  = threadIdx.x;
    const int w    = tid >> 6;
    const int lane = tid & 63;
    const int quad = lane >> 4, c = lane & 15;

    __shared__ __align__(16) f16 Ks[64][72];
    __shared__ __align__(16) f16 Vts[64][72];
    __shared__ __align__(16) f16 Pw[4][32][72];
    __shared__ float tab[NREL];

    const size_t base = (size_t)bh << 16;

    // tab pre-scaled by log2e: exp(s+t) == exp2(s*log2e + t*log2e)
    for (int i = tid; i < NREL; i += 256) tab[i] = Tab[h * NREL + i] * LOG2E;

    const int qg0 = q0 + (w << 5);
    half8 Aq[2][2];
#pragma unroll
    for (int s = 0; s < 2; ++s) {
        const f16* qp = Q + base + (size_t)(qg0 + s * 16 + c) * 64 + quad * 8;
        Aq[s][0] = *reinterpret_cast<const half8*>(qp);
        Aq[s][1] = *reinterpret_cast<const half8*>(qp + 32);
    }

    floatx4 o[2][4] = {};
    float l_part[2][4] = {};

    const int* rp = RPE + (size_t)(qg0 + (quad << 2)) * 1024 + c;

    const int sr = tid >> 2, so = (tid & 3) << 4;
    const f16* kbase = K  + base + (size_t)sr * 64 + so;
    const f16* vbase = Vt + base + (size_t)sr * 1024 + so;

    uint4 pk0 = *reinterpret_cast<const uint4*>(kbase);
    uint4 pk1 = *reinterpret_cast<const uint4*>(kbase + 8);
    uint4 pv0 = *reinterpret_cast<const uint4*>(vbase);
    uint4 pv1 = *reinterpret_cast<const uint4*>(vbase + 8);

    // idx prefetch for j0 = 0 (consumed in iter 0's exp section)
    int idx[2][4][4];
#pragma unroll
    for (int s = 0; s < 2; ++s)
#pragma unroll
        for (int r = 0; r < 4; ++r)
#pragma unroll
            for (int nt = 0; nt < 4; ++nt)
                idx[s][r][nt] = rp[(size_t)(s * 16 + r) * 1024 + nt * 16];

    for (int j0 = 0; j0 < L_SEQ; j0 += 64) {
        __syncthreads();
        *reinterpret_cast<uint4*>(&Ks[sr][so])      = pk0;
        *reinterpret_cast<uint4*>(&Ks[sr][so + 8])  = pk1;
        *reinterpret_cast<uint4*>(&Vts[sr][so])     = pv0;
        *reinterpret_cast<uint4*>(&Vts[sr][so + 8]) = pv1;
        __syncthreads();

        if (j0 + 64 < L_SEQ) {
            const f16* kn = kbase + (size_t)(j0 + 64) * 64;
            const f16* vn = vbase + (j0 + 64);
            pk0 = *reinterpret_cast<const uint4*>(kn);
            pk1 = *reinterpret_cast<const uint4*>(kn + 8);
            pv0 = *reinterpret_cast<const uint4*>(vn);
            pv1 = *reinterpret_cast<const uint4*>(vn + 8);
        }

        floatx4 sc[2][4];
#pragma unroll
        for (int nt = 0; nt < 4; ++nt) {
            const half8 b0 = *reinterpret_cast<const half8*>(&Ks[nt * 16 + c][quad * 8]);
            const half8 b1 = *reinterpret_cast<const half8*>(&Ks[nt * 16 + c][32 + quad * 8]);
            floatx4 t0 = {}, t1 = {};
            t0 = __builtin_amdgcn_mfma_f32_16x16x32_f16(Aq[0][0], b0, t0, 0, 0, 0);
            t0 = __builtin_amdgcn_mfma_f32_16x16x32_f16(Aq[0][1], b1, t0, 0, 0, 0);
            t1 = __builtin_amdgcn_mfma_f32_16x16x32_f16(Aq[1][0], b0, t1, 0, 0, 0);
            t1 = __builtin_amdgcn_mfma_f32_16x16x32_f16(Aq[1][1], b1, t1, 0, 0, 0);
            sc[0][nt] = t0; sc[1][nt] = t1;
        }

#pragma unroll
        for (int s = 0; s < 2; ++s)
#pragma unroll
            for (int r = 0; r < 4; ++r) {
                float rs = 0.0f;
#pragma unroll
                for (int nt = 0; nt < 4; ++nt) {
                    const float p = exp2f(sc[s][nt][r] + tab[idx[s][r][nt]]);
                    rs += p;
                    Pw[w][s * 16 + quad * 4 + r][nt * 16 + c] = (f16)p;
                }
                l_part[s][r] += rs;
            }

        // idx loads for next j-tile: issued here so latency hides under PV +
        // barriers + staging + QK^T of the next iteration (was exposed ~200cy).
        if (j0 + 64 < L_SEQ) {
#pragma unroll
            for (int s = 0; s < 2; ++s)
#pragma unroll
                for (int r = 0; r < 4; ++r)
#pragma unroll
                    for (int nt = 0; nt < 4; ++nt)
                        idx[s][r][nt] = rp[(size_t)(s * 16 + r) * 1024 + j0 + 64 + nt * 16];
        }

        half8 vb[4][2];
#pragma unroll
        for (int nt = 0; nt < 4; ++nt) {
            vb[nt][0] = *reinterpret_cast<const half8*>(&Vts[nt * 16 + c][quad * 8]);
            vb[nt][1] = *reinterpret_cast<const half8*>(&Vts[nt * 16 + c][32 + quad * 8]);
        }
#pragma unroll
        for (int s = 0; s < 2; ++s) {
            const half8 Ap0 = *reinterpret_cast<const half8*>(&Pw[w][s * 16 + c][quad * 8]);
            const half8 Ap1 = *reinterpret_cast<const half8*>(&Pw[w][s * 16 + c][32 + quad * 8]);
#pragma unroll
            for (int nt = 0; nt < 4; ++nt) {
                o[s][nt] = __builtin_amdgcn_mfma_f32_16x16x32_f16(Ap0, vb[nt][0], o[s][nt], 0, 0, 0);
                o[s][nt] = __builtin_amdgcn_mfma_f32_16x16x32_f16(Ap1, vb[nt][1], o[s][nt], 0, 0, 0);
            }
        }
    }

#pragma unroll
    for (int s = 0; s < 2; ++s)
#pragma unroll
        for (int r = 0; r < 4; ++r) {
            float l = l_part[s][r];
            l += __shfl_xor(l, 1); l += __shfl_xor(l, 2);
            l += __shfl_xor(l, 4); l += __shfl_xor(l, 8);
            const float inv = 1.0f / l;
            const int lrow = qg0 + s * 16 + quad * 4 + r;
            f16* dp = CTX + ((size_t)(lrow * 16 + b)) * 512 + h * 64;
#pragma unroll
            for (int nt = 0; nt < 4; ++nt)
                dp[nt * 16 + c] = (f16)(o[s][nt][r] * inv);
        }
}

// ---------------------------------------------------------------------------
// Stage 4: out_proj MFMA GEMM. 512 blocks, XCD-swizzled, R10 pipeline.
// A = CTX (f16 pass-through regs); B = W (fp32 -> cvt at write).
// ---------------------------------------------------------------------------
__global__ __launch_bounds__(256) void out_kernel(
    const f16* __restrict__ X, const float* __restrict__ W, const float* __restrict__ Bias,
    float* __restrict__ Out)
{
    // swizzle: 16 m-groups per XCD, 4 f-tiles per group on same XCD
    const int flat = blockIdx.x;
    const int xcd  = flat & 7;
    const int slot = flat >> 3;            // 0..63
    const int m    = xcd * 16 + (slot >> 2);   // 0..127
    const int f0   = (slot & 3) << 7;
    const int n0   = m << 7;

    __shared__ __align__(16) f16 As[2][128][40];
    __shared__ __align__(16) f16 Bs[2][128][40];

    const int tid  = threadIdx.x;
    const int w    = tid >> 6;
    const int lane = tid & 63;
    const int quad = lane >> 4, c = lane & 15;
    const int wm = (w >> 1) << 6, wn = (w & 1) << 6;

    // A staging (f16): instr i: row = w*32 + i*16 + (lane>>2), col = (lane&3)*8
    const int arow = (w << 5) + (lane >> 2);     // + i*16
    const int acol = (lane & 3) << 3;
    const f16* Xg = X + (size_t)(n0 + arow) * E_DIM + acol;

    // B staging (fp32): as qkv
    const int srow = (w << 5) + (lane >> 3);     // + i*8
    const int scol = (lane & 7) << 2;
    const float* Wg = W + (size_t)(f0 + srow) * E_DIM + scol;

    uint4  la[2];
    float4 lw[4];
    auto load_tile = [&](int kk) {
#pragma unroll
        for (int i = 0; i < 2; ++i)
            la[i] = *reinterpret_cast<const uint4*>(Xg + (size_t)(i * 16) * E_DIM + kk);
#pragma unroll
        for (int i = 0; i < 4; ++i)
            lw[i] = *reinterpret_cast<const float4*>(Wg + (size_t)(i * 8) * E_DIM + kk);
    };
    auto write_tile = [&](int buf) {
#pragma unroll
        for (int i = 0; i < 2; ++i)
            *reinterpret_cast<uint4*>(&As[buf][arow + i * 16][acol]) = la[i];
#pragma unroll
        for (int i = 0; i < 4; ++i)
            *reinterpret_cast<half4*>(&Bs[buf][srow + i * 8][scol]) = cvt4(lw[i]);
    };

    floatx4 acc[4][4] = {};

    load_tile(0);
    write_tile(0);
    load_tile(32);
    LGKM_BARRIER();

    for (int t = 0; t < 16; ++t) {
        const int cur = t & 1;

        half8 a[4], bfr[4];
#pragma unroll
        for (int mt = 0; mt < 4; ++mt)
            a[mt] = *reinterpret_cast<const half8*>(&As[cur][wm + mt * 16 + c][quad * 8]);
#pragma unroll
        for (int nt = 0; nt < 4; ++nt)
            bfr[nt] = *reinterpret_cast<const half8*>(&Bs[cur][wn + nt * 16 + c][quad * 8]);
#pragma unroll
        for (int mt = 0; mt < 4; ++mt)
#pragma unroll
            for (int nt = 0; nt < 4; ++nt)
                acc[mt][nt] = __builtin_amdgcn_mfma_f32_16x16x32_f16(a[mt], bfr[nt], acc[mt][nt], 0, 0, 0);

        if (t < 15) {
            write_tile(cur ^ 1);
            if (t < 14) load_tile((t + 2) * 32);
        }
        LGKM_BARRIER();
    }

#pragma unroll
    for (int nt = 0; nt < 4; ++nt) {
        const int f = f0 + wn + nt * 16 + c;
        const float bj = Bias[f];
#pragma unroll
        for (int mt = 0; mt < 4; ++mt) {
#pragma unroll
            for (int r = 0; r < 4; ++r) {
                const int n = n0 + wm + mt * 16 + quad * 4 + r;
                Out[(size_t)n * E_DIM + f] = acc[mt][nt][r] + bj;
            }
        }
    }
}

// ---------------------------------------------------------------------------
extern "C" void kernel_launch(void* const* d_in, const int* in_sizes, int n_in,
                              void* d_out, int out_size, void* d_ws, size_t ws_size,
                              hipStream_t stream) {
    const float* q_in = (const float*)d_in[0];
    const float* k_in = (const float*)d_in[1];
    const float* v_in = (const float*)d_in[2];
    const float* ipw  = (const float*)d_in[3];
    const float* ipb  = (const float*)d_in[4];
    const float* opw  = (const float*)d_in[5];
    const float* opb  = (const float*)d_in[6];
    const float* tab  = (const float*)d_in[7];
    const int*   rpe  = (const int*)d_in[8];
    float* out = (float*)d_out;

    f16* ws   = (f16*)d_ws;
    f16* Q    = ws;
    f16* K    = ws + 8388608;
    f16* Vt   = ws + 16777216;
    f16* Vtmp = ws + 25165824;
    f16* CTX  = ws + 25165824;

    qkv_kernel<<<dim3(1536), 256, 0, stream>>>(q_in, k_in, v_in, ipw, ipb, Q, K, Vtmp);
    transpose_v<<<dim3(16, 128), 256, 0, stream>>>(Vtmp, Vt);
    attn_kernel<<<dim3(1024), 256, 0, stream>>>(Q, K, Vt, rpe, tab, CTX);
    out_kernel<<<dim3(512), 256, 0, stream>>>(CTX, opw, opb, out);
}

// Round 7
// 324.959 us; speedup vs baseline: 1.1956x; 1.0238x over previous
//
#include <hip/hip_runtime.h>
#include <hip/hip_bf16.h>

// MultiheadAttention with relative position bias, MI355X gfx950.
// L=1024, B=16, E=512, H=8, d=64. Inputs/output fp32; ws intermediates fp16.
//
// Stage 1: qkv_kernel   -- MFMA in_proj GEMMs -> Q,K,V fp16, (B,H,L,64),
//                          q pre-scaled 1/8*log2e (exp2 base-change folding)
//                          R10: f16 reg-staged LDS, raw-barrier pipeline
// Stage 2: transpose_v  -- V (B,H,L,64) -> Vt (B,H,64,L) for MFMA B-operand
// Stage 3: attn_kernel  -- MFMA flash attention w/ RPE bias -> CTX fp16 (L,B,E)
//                          R14 (= R13 resubmit; infra failure, never measured):
//                          hardware exp2 via __builtin_amdgcn_exp2f (R12's exp2f
//                          lowered to OCML precise exp2 = 5 VALU/call w/ denormal
//                          fixup, +26us; add+v_exp is 2) + idx prefetch 1 tile ahead
// Stage 4: out_kernel   -- MFMA out_proj GEMM -> fp32 output (L,B,E), R10 pipeline
//
// ws (fp16 elems): Q @0, K @8M, Vt @16M, Vtmp/CTX @24M (aliased, disjoint lifetimes).
//
// MFMA f16 16x16x32 layouts (verified end-to-end in this problem, round 4):
//   A[m=lane&15][k=quad*8+j], B[k=quad*8+j][n=lane&15], D[row=quad*4+reg][col=lane&15]

#define L_SEQ 1024
#define B_N   16
#define E_DIM 512
#define H_N   8
#define NREL  2047
#define LOG2E 1.44269504f

typedef _Float16 f16;
using half4   = __attribute__((ext_vector_type(4))) _Float16;
using half8   = __attribute__((ext_vector_type(8))) _Float16;
using floatx4 = __attribute__((ext_vector_type(4))) float;

// lgkmcnt(0) drain (ds_write visibility) + raw barrier, pinned against code motion.
// Does NOT drain vmcnt -> global loads stay in flight across the barrier.
#define LGKM_BARRIER() do {                                   \
    asm volatile("s_waitcnt lgkmcnt(0)" ::: "memory");        \
    __builtin_amdgcn_sched_barrier(0);                        \
    __builtin_amdgcn_s_barrier();                             \
    __builtin_amdgcn_sched_barrier(0);                        \
} while (0)

// raw hardware exp2 (single v_exp_f32; ~1ulp, no denormal fixup -- inputs O(10)).
__device__ __forceinline__ float fast_exp2(float x) {
    return __builtin_amdgcn_exp2f(x);
}

__device__ __forceinline__ half4 cvt4(const float4 a) {
    half4 h;
    h[0] = (f16)a.x; h[1] = (f16)a.y; h[2] = (f16)a.z; h[3] = (f16)a.w;
    return h;
}

// ---------------------------------------------------------------------------
// Stage 1: in_proj MFMA GEMM. 1536 blocks, XCD-swizzled so the 4 f-tile
// blocks sharing an X row-slice land on one XCD (same L2).
// Pipeline per iter: compute(buf[t&1]) ; cvt+write(t+1) ; issue loads(t+2) ;
// lgkmcnt(0)+s_barrier.  Loads issued at iter t are consumed at iter t+1's
// write phase -> ~1 barrier + 1 compute phase of latency cover.
// ---------------------------------------------------------------------------
__global__ __launch_bounds__(256) void qkv_kernel(
    const float* __restrict__ Xq, const float* __restrict__ Xk, const float* __restrict__ Xv,
    const float* __restrict__ W, const float* __restrict__ Bias,
    f16* __restrict__ Qo, f16* __restrict__ Ko, f16* __restrict__ Vo)
{
    // swizzle: xcd = flat&7; 48 groups (m,proj) per XCD; 4 f-tiles per group
    const int flat = blockIdx.x;
    const int xcd  = flat & 7;
    const int slot = flat >> 3;            // 0..191
    const int g    = xcd * 48 + (slot >> 2);   // 0..383 = proj*128 + mtile
    const int f0   = (slot & 3) << 7;
    const int proj = g >> 7;               // 0=q 1=k 2=v
    const int n0   = (g & 127) << 7;

    const float* X  = (proj == 0) ? Xq : (proj == 1) ? Xk : Xv;
    const float* Wp = W + (size_t)(proj << 9) * E_DIM;

    // f16 tiles, padded rows (40 f16 = 80 B -> bank spread), double-buffered. 40 KB.
    __shared__ __align__(16) f16 As[2][128][40];
    __shared__ __align__(16) f16 Bs[2][128][40];

    const int tid  = threadIdx.x;
    const int w    = tid >> 6;
    const int lane = tid & 63;
    const int quad = lane >> 4, c = lane & 15;
    const int wm = (w >> 1) << 6, wn = (w & 1) << 6;

    // staging: wave w covers rows [w*32, w*32+32); instr i: row = w*32+i*8+(lane>>3),
    // cols (lane&7)*4 .. +3 (fp32) -> 8 rows x 128 B contiguous segments per instr.
    const int srow = (w << 5) + (lane >> 3);     // + i*8
    const int scol = (lane & 7) << 2;
    const float* Xg = X  + (size_t)(n0 + srow) * E_DIM + scol;
    const float* Wg = Wp + (size_t)(f0 + srow) * E_DIM + scol;

    float4 lx[4], lw[4];
    auto load_tile = [&](int kk) {
#pragma unroll
        for (int i = 0; i < 4; ++i)
            lx[i] = *reinterpret_cast<const float4*>(Xg + (size_t)(i * 8) * E_DIM + kk);
#pragma unroll
        for (int i = 0; i < 4; ++i)
            lw[i] = *reinterpret_cast<const float4*>(Wg + (size_t)(i * 8) * E_DIM + kk);
    };
    auto write_tile = [&](int buf) {
#pragma unroll
        for (int i = 0; i < 4; ++i)
            *reinterpret_cast<half4*>(&As[buf][srow + i * 8][scol]) = cvt4(lx[i]);
#pragma unroll
        for (int i = 0; i < 4; ++i)
            *reinterpret_cast<half4*>(&Bs[buf][srow + i * 8][scol]) = cvt4(lw[i]);
    };

    floatx4 acc[4][4] = {};

    // prologue: tile0 staged+visible; tile1 loads in flight
    load_tile(0);
    write_tile(0);
    load_tile(32);
    LGKM_BARRIER();

    for (int t = 0; t < 16; ++t) {
        const int cur = t & 1;

        half8 a[4], bfr[4];
#pragma unroll
        for (int mt = 0; mt < 4; ++mt)
            a[mt] = *reinterpret_cast<const half8*>(&As[cur][wm + mt * 16 + c][quad * 8]);
#pragma unroll
        for (int nt = 0; nt < 4; ++nt)
            bfr[nt] = *reinterpret_cast<const half8*>(&Bs[cur][wn + nt * 16 + c][quad * 8]);
#pragma unroll
        for (int mt = 0; mt < 4; ++mt)
#pragma unroll
            for (int nt = 0; nt < 4; ++nt)
                acc[mt][nt] = __builtin_amdgcn_mfma_f32_16x16x32_f16(a[mt], bfr[nt], acc[mt][nt], 0, 0, 0);

        if (t < 15) {
            write_tile(cur ^ 1);               // cvt consumes loads(t+1); auto vmcnt wait
            if (t < 14) load_tile((t + 2) * 32);  // regs free -> issue next, flies over barrier
        }
        LGKM_BARRIER();
    }

    f16* Dst = (proj == 0) ? Qo : (proj == 1) ? Ko : Vo;
    // q pre-scale folds softmax base-change: exp(x) = exp2(x*log2e)
    const float scale = (proj == 0) ? (0.125f * LOG2E) : 1.0f;

#pragma unroll
    for (int nt = 0; nt < 4; ++nt) {
        const int fl = f0 + wn + nt * 16 + c;
        const float bj = Bias[(proj << 9) + fl];
        const int h = fl >> 6, d = fl & 63;
#pragma unroll
        for (int mt = 0; mt < 4; ++mt) {
#pragma unroll
            for (int r = 0; r < 4; ++r) {
                const int n = n0 + wm + mt * 16 + quad * 4 + r;
                const int l = n >> 4, b = n & 15;
                Dst[((((size_t)b * H_N + h) * L_SEQ + l) << 6) + d] =
                    (f16)((acc[mt][nt][r] + bj) * scale);
            }
        }
    }
}

// ---------------------------------------------------------------------------
// Stage 2: V (b,h)[l][d] -> Vt (b,h)[d][l]. grid (16, 128), block 256.
// ---------------------------------------------------------------------------
__global__ __launch_bounds__(256) void transpose_v(
    const f16* __restrict__ V, f16* __restrict__ Vt)
{
    const int l0 = blockIdx.x << 6;
    const size_t base = (size_t)blockIdx.y << 16;
    __shared__ __align__(16) f16 T[64][72];
    const int tid = threadIdx.x;
    const int r = tid >> 2, co = (tid & 3) << 4;

    const uint4 a0 = *reinterpret_cast<const uint4*>(V + base + (size_t)(l0 + r) * 64 + co);
    const uint4 a1 = *reinterpret_cast<const uint4*>(V + base + (size_t)(l0 + r) * 64 + co + 8);
    *reinterpret_cast<uint4*>(&T[r][co])     = a0;
    *reinterpret_cast<uint4*>(&T[r][co + 8]) = a1;
    __syncthreads();

    union { f16 h[16]; uint4 u[2]; } pk;
#pragma unroll
    for (int j = 0; j < 16; ++j) pk.h[j] = T[co + j][r];
    *reinterpret_cast<uint4*>(Vt + base + (size_t)r * 1024 + l0 + co)     = pk.u[0];
    *reinterpret_cast<uint4*>(Vt + base + (size_t)r * 1024 + l0 + co + 8) = pk.u[1];
}

// ---------------------------------------------------------------------------
// Stage 3: MFMA flash attention, fixed-max softmax. 1024 blocks, block 256.
// R14: R10 staged body + hardware exp2 (tab pre-scaled log2e; Q pre-scaled in
// qkv) + idx loads for j0+64 issued after the exp section (covered by PV +
// barriers + staging + QK^T instead of exposed ~200cy after the staging barrier).
// XCD swizzle: the 8 q-tile blocks of each (b,h) share K/V through one L2.
// ---------------------------------------------------------------------------
__global__ __launch_bounds__(256, 3) void attn_kernel(
    const f16* __restrict__ Q, const f16* __restrict__ K, const f16* __restrict__ Vt,
    const int* __restrict__ RPE, const float* __restrict__ Tab, f16* __restrict__ CTX)
{
    // swizzle: xcd = flat&7; bh = (slot>>3)*8 + xcd; q-tile = slot&7
    const int flat = blockIdx.x;
    const int xcd  = flat & 7;
    const int slot = flat >> 3;            // 0..127
    const int q0   = (slot & 7) << 7;
    const int bh   = ((slot >> 3) << 3) + xcd;
    const int b = bh >> 3, h = bh & 7;

    const int tid  = threadIdx.x;
    const int w    = tid >> 6;
    const int lane = tid & 63;
    const int quad = lane >> 4, c = lane & 15;

    __shared__ __align__(16) f16 Ks[64][72];
    __shared__ __align__(16) f16 Vts[64][72];
    __shared__ __align__(16) f16 Pw[4][32][72];
    __shared__ float tab[NREL];

    const size_t base = (size_t)bh << 16;

    // tab pre-scaled by log2e: exp(s+t) == exp2(s*log2e + t*log2e)
    for (int i = tid; i < NREL; i += 256) tab[i] = Tab[h * NREL + i] * LOG2E;

    const int qg0 = q0 + (w << 5);
    half8 Aq[2][2];
#pragma unroll
    for (int s = 0; s < 2; ++s) {
        const f16* qp = Q + base + (size_t)(qg0 + s * 16 + c) * 64 + quad * 8;
        Aq[s][0] = *reinterpret_cast<const half8*>(qp);
        Aq[s][1] = *reinterpret_cast<const half8*>(qp + 32);
    }

    floatx4 o[2][4] = {};
    float l_part[2][4] = {};

    const int* rp = RPE + (size_t)(qg0 + (quad << 2)) * 1024 + c;

    const int sr = tid >> 2, so = (tid & 3) << 4;
    const f16* kbase = K  + base + (size_t)sr * 64 + so;
    const f16* vbase = Vt + base + (size_t)sr * 1024 + so;

    uint4 pk0 = *reinterpret_cast<const uint4*>(kbase);
    uint4 pk1 = *reinterpret_cast<const uint4*>(kbase + 8);
    uint4 pv0 = *reinterpret_cast<const uint4*>(vbase);
    uint4 pv1 = *reinterpret_cast<const uint4*>(vbase + 8);

    // idx prefetch for j0 = 0 (consumed in iter 0's exp section)
    int idx[2][4][4];
#pragma unroll
    for (int s = 0; s < 2; ++s)
#pragma unroll
        for (int r = 0; r < 4; ++r)
#pragma unroll
            for (int nt = 0; nt < 4; ++nt)
                idx[s][r][nt] = rp[(size_t)(s * 16 + r) * 1024 + nt * 16];

    for (int j0 = 0; j0 < L_SEQ; j0 += 64) {
        __syncthreads();
        *reinterpret_cast<uint4*>(&Ks[sr][so])      = pk0;
        *reinterpret_cast<uint4*>(&Ks[sr][so + 8])  = pk1;
        *reinterpret_cast<uint4*>(&Vts[sr][so])     = pv0;
        *reinterpret_cast<uint4*>(&Vts[sr][so + 8]) = pv1;
        __syncthreads();

        if (j0 + 64 < L_SEQ) {
            const f16* kn = kbase + (size_t)(j0 + 64) * 64;
            const f16* vn = vbase + (j0 + 64);
            pk0 = *reinterpret_cast<const uint4*>(kn);
            pk1 = *reinterpret_cast<const uint4*>(kn + 8);
            pv0 = *reinterpret_cast<const uint4*>(vn);
            pv1 = *reinterpret_cast<const uint4*>(vn + 8);
        }

        floatx4 sc[2][4];
#pragma unroll
        for (int nt = 0; nt < 4; ++nt) {
            const half8 b0 = *reinterpret_cast<const half8*>(&Ks[nt * 16 + c][quad * 8]);
            const half8 b1 = *reinterpret_cast<const half8*>(&Ks[nt * 16 + c][32 + quad * 8]);
            floatx4 t0 = {}, t1 = {};
            t0 = __builtin_amdgcn_mfma_f32_16x16x32_f16(Aq[0][0], b0, t0, 0, 0, 0);
            t0 = __builtin_amdgcn_mfma_f32_16x16x32_f16(Aq[0][1], b1, t0, 0, 0, 0);
            t1 = __builtin_amdgcn_mfma_f32_16x16x32_f16(Aq[1][0], b0, t1, 0, 0, 0);
            t1 = __builtin_amdgcn_mfma_f32_16x16x32_f16(Aq[1][1], b1, t1, 0, 0, 0);
            sc[0][nt] = t0; sc[1][nt] = t1;
        }

#pragma unroll
        for (int s = 0; s < 2; ++s)
#pragma unroll
            for (int r = 0; r < 4; ++r) {
                float rs = 0.0f;
#pragma unroll
                for (int nt = 0; nt < 4; ++nt) {
                    const float p = fast_exp2(sc[s][nt][r] + tab[idx[s][r][nt]]);
                    rs += p;
                    Pw[w][s * 16 + quad * 4 + r][nt * 16 + c] = (f16)p;
                }
                l_part[s][r] += rs;
            }

        // idx loads for next j-tile: issued here so latency hides under PV +
        // barriers + staging + QK^T of the next iteration (was exposed ~200cy).
        if (j0 + 64 < L_SEQ) {
#pragma unroll
            for (int s = 0; s < 2; ++s)
#pragma unroll
                for (int r = 0; r < 4; ++r)
#pragma unroll
                    for (int nt = 0; nt < 4; ++nt)
                        idx[s][r][nt] = rp[(size_t)(s * 16 + r) * 1024 + j0 + 64 + nt * 16];
        }

        half8 vb[4][2];
#pragma unroll
        for (int nt = 0; nt < 4; ++nt) {
            vb[nt][0] = *reinterpret_cast<const half8*>(&Vts[nt * 16 + c][quad * 8]);
            vb[nt][1] = *reinterpret_cast<const half8*>(&Vts[nt * 16 + c][32 + quad * 8]);
        }
#pragma unroll
        for (int s = 0; s < 2; ++s) {
            const half8 Ap0 = *reinterpret_cast<const half8*>(&Pw[w][s * 16 + c][quad * 8]);
            const half8 Ap1 = *reinterpret_cast<const half8*>(&Pw[w][s * 16 + c][32 + quad * 8]);
#pragma unroll
            for (int nt = 0; nt < 4; ++nt) {
                o[s][nt] = __builtin_amdgcn_mfma_f32_16x16x32_f16(Ap0, vb[nt][0], o[s][nt], 0, 0, 0);
                o[s][nt] = __builtin_amdgcn_mfma_f32_16x16x32_f16(Ap1, vb[nt][1], o[s][nt], 0, 0, 0);
            }
        }
    }

#pragma unroll
    for (int s = 0; s < 2; ++s)
#pragma unroll
        for (int r = 0; r < 4; ++r) {
            float l = l_part[s][r];
            l += __shfl_xor(l, 1); l += __shfl_xor(l, 2);
            l += __shfl_xor(l, 4); l += __shfl_xor(l, 8);
            const float inv = 1.0f / l;
            const int lrow = qg0 + s * 16 + quad * 4 + r;
            f16* dp = CTX + ((size_t)(lrow * 16 + b)) * 512 + h * 64;
#pragma unroll
            for (int nt = 0; nt < 4; ++nt)
                dp[nt * 16 + c] = (f16)(o[s][nt][r] * inv);
        }
}

// ---------------------------------------------------------------------------
// Stage 4: out_proj MFMA GEMM. 512 blocks, XCD-swizzled, R10 pipeline.
// A = CTX (f16 pass-through regs); B = W (fp32 -> cvt at write).
// ---------------------------------------------------------------------------
__global__ __launch_bounds__(256) void out_kernel(
    const f16* __restrict__ X, const float* __restrict__ W, const float* __restrict__ Bias,
    float* __restrict__ Out)
{
    // swizzle: 16 m-groups per XCD, 4 f-tiles per group on same XCD
    const int flat = blockIdx.x;
    const int xcd  = flat & 7;
    const int slot = flat >> 3;            // 0..63
    const int m    = xcd * 16 + (slot >> 2);   // 0..127
    const int f0   = (slot & 3) << 7;
    const int n0   = m << 7;

    __shared__ __align__(16) f16 As[2][128][40];
    __shared__ __align__(16) f16 Bs[2][128][40];

    const int tid  = threadIdx.x;
    const int w    = tid >> 6;
    const int lane = tid & 63;
    const int quad = lane >> 4, c = lane & 15;
    const int wm = (w >> 1) << 6, wn = (w & 1) << 6;

    // A staging (f16): instr i: row = w*32 + i*16 + (lane>>2), col = (lane&3)*8
    const int arow = (w << 5) + (lane >> 2);     // + i*16
    const int acol = (lane & 3) << 3;
    const f16* Xg = X + (size_t)(n0 + arow) * E_DIM + acol;

    // B staging (fp32): as qkv
    const int srow = (w << 5) + (lane >> 3);     // + i*8
    const int scol = (lane & 7) << 2;
    const float* Wg = W + (size_t)(f0 + srow) * E_DIM + scol;

    uint4  la[2];
    float4 lw[4];
    auto load_tile = [&](int kk) {
#pragma unroll
        for (int i = 0; i < 2; ++i)
            la[i] = *reinterpret_cast<const uint4*>(Xg + (size_t)(i * 16) * E_DIM + kk);
#pragma unroll
        for (int i = 0; i < 4; ++i)
            lw[i] = *reinterpret_cast<const float4*>(Wg + (size_t)(i * 8) * E_DIM + kk);
    };
    auto write_tile = [&](int buf) {
#pragma unroll
        for (int i = 0; i < 2; ++i)
            *reinterpret_cast<uint4*>(&As[buf][arow + i * 16][acol]) = la[i];
#pragma unroll
        for (int i = 0; i < 4; ++i)
            *reinterpret_cast<half4*>(&Bs[buf][srow + i * 8][scol]) = cvt4(lw[i]);
    };

    floatx4 acc[4][4] = {};

    load_tile(0);
    write_tile(0);
    load_tile(32);
    LGKM_BARRIER();

    for (int t = 0; t < 16; ++t) {
        const int cur = t & 1;

        half8 a[4], bfr[4];
#pragma unroll
        for (int mt = 0; mt < 4; ++mt)
            a[mt] = *reinterpret_cast<const half8*>(&As[cur][wm + mt * 16 + c][quad * 8]);
#pragma unroll
        for (int nt = 0; nt < 4; ++nt)
            bfr[nt] = *reinterpret_cast<const half8*>(&Bs[cur][wn + nt * 16 + c][quad * 8]);
#pragma unroll
        for (int mt = 0; mt < 4; ++mt)
#pragma unroll
            for (int nt = 0; nt < 4; ++nt)
                acc[mt][nt] = __builtin_amdgcn_mfma_f32_16x16x32_f16(a[mt], bfr[nt], acc[mt][nt], 0, 0, 0);

        if (t < 15) {
            write_tile(cur ^ 1);
            if (t < 14) load_tile((t + 2) * 32);
        }
        LGKM_BARRIER();
    }

#pragma unroll
    for (int nt = 0; nt < 4; ++nt) {
        const int f = f0 + wn + nt * 16 + c;
        const float bj = Bias[f];
#pragma unroll
        for (int mt = 0; mt < 4; ++mt) {
#pragma unroll
            for (int r = 0; r < 4; ++r) {
                const int n = n0 + wm + mt * 16 + quad * 4 + r;
                Out[(size_t)n * E_DIM + f] = acc[mt][nt][r] + bj;
            }
        }
    }
}

// ---------------------------------------------------------------------------
extern "C" void kernel_launch(void* const* d_in, const int* in_sizes, int n_in,
                              void* d_out, int out_size, void* d_ws, size_t ws_size,
                              hipStream_t stream) {
    const float* q_in = (const float*)d_in[0];
    const float* k_in = (const float*)d_in[1];
    const float* v_in = (const float*)d_in[2];
    const float* ipw  = (const float*)d_in[3];
    const float* ipb  = (const float*)d_in[4];
    const float* opw  = (const float*)d_in[5];
    const float* opb  = (const float*)d_in[6];
    const float* tab  = (const float*)d_in[7];
    const int*   rpe  = (const int*)d_in[8];
    float* out = (float*)d_out;

    f16* ws   = (f16*)d_ws;
    f16* Q    = ws;
    f16* K    = ws + 8388608;
    f16* Vt   = ws + 16777216;
    f16* Vtmp = ws + 25165824;
    f16* CTX  = ws + 25165824;

    qkv_kernel<<<dim3(1536), 256, 0, stream>>>(q_in, k_in, v_in, ipw, ipb, Q, K, Vtmp);
    transpose_v<<<dim3(16, 128), 256, 0, stream>>>(Vtmp, Vt);
    attn_kernel<<<dim3(1024), 256, 0, stream>>>(Q, K, Vt, rpe, tab, CTX);
    out_kernel<<<dim3(512), 256, 0, stream>>>(CTX, opw, opb, out);
}

// Round 8
// 309.970 us; speedup vs baseline: 1.2534x; 1.0484x over previous
//
#include <hip/hip_runtime.h>
#include <hip/hip_bf16.h>

// MultiheadAttention with relative position bias, MI355X gfx950.
// L=1024, B=16, E=512, H=8, d=64. Inputs/output fp32; ws intermediates fp16.
//
// Stage 1: qkv_kernel   -- MFMA in_proj GEMMs -> Q,K,V fp16, (B,H,L,64),
//                          q pre-scaled 1/8*log2e (exp2 base-change folding)
//                          R10: f16 reg-staged LDS, raw-barrier pipeline
// Stage 2: transpose_v  -- V (B,H,L,64) -> Vt (B,H,64,L) for MFMA B-operand
// Stage 3: attn_kernel  -- MFMA flash attention w/ RPE bias -> CTX fp16 (L,B,E)
//                          R15: R10 body w/ in-loop idx loads (the R12/R14 idx
//                          prefetch let the compiler hoist conflicted tab gathers
//                          into QK^T's lgkmcnt shadow -> MFMA starved, +15us;
//                          in-loop idx vmcnt-fences gathers after QK^T)
//                          + hardware exp2 (confirmed -9pts VALUBusy in R14)
// Stage 4: out_kernel   -- MFMA out_proj GEMM -> fp32 output (L,B,E), R10 pipeline
//
// ws (fp16 elems): Q @0, K @8M, Vt @16M, Vtmp/CTX @24M (aliased, disjoint lifetimes).
//
// MFMA f16 16x16x32 layouts (verified end-to-end in this problem, round 4):
//   A[m=lane&15][k=quad*8+j], B[k=quad*8+j][n=lane&15], D[row=quad*4+reg][col=lane&15]

#define L_SEQ 1024
#define B_N   16
#define E_DIM 512
#define H_N   8
#define NREL  2047
#define LOG2E 1.44269504f

typedef _Float16 f16;
using half4   = __attribute__((ext_vector_type(4))) _Float16;
using half8   = __attribute__((ext_vector_type(8))) _Float16;
using floatx4 = __attribute__((ext_vector_type(4))) float;

// lgkmcnt(0) drain (ds_write visibility) + raw barrier, pinned against code motion.
// Does NOT drain vmcnt -> global loads stay in flight across the barrier.
#define LGKM_BARRIER() do {                                   \
    asm volatile("s_waitcnt lgkmcnt(0)" ::: "memory");        \
    __builtin_amdgcn_sched_barrier(0);                        \
    __builtin_amdgcn_s_barrier();                             \
    __builtin_amdgcn_sched_barrier(0);                        \
} while (0)

// raw hardware exp2 (single v_exp_f32; ~1ulp, no denormal fixup -- inputs O(10)).
__device__ __forceinline__ float fast_exp2(float x) {
    return __builtin_amdgcn_exp2f(x);
}

__device__ __forceinline__ half4 cvt4(const float4 a) {
    half4 h;
    h[0] = (f16)a.x; h[1] = (f16)a.y; h[2] = (f16)a.z; h[3] = (f16)a.w;
    return h;
}

// ---------------------------------------------------------------------------
// Stage 1: in_proj MFMA GEMM. 1536 blocks, XCD-swizzled so the 4 f-tile
// blocks sharing an X row-slice land on one XCD (same L2).
// Pipeline per iter: compute(buf[t&1]) ; cvt+write(t+1) ; issue loads(t+2) ;
// lgkmcnt(0)+s_barrier.  Loads issued at iter t are consumed at iter t+1's
// write phase -> ~1 barrier + 1 compute phase of latency cover.
// ---------------------------------------------------------------------------
__global__ __launch_bounds__(256) void qkv_kernel(
    const float* __restrict__ Xq, const float* __restrict__ Xk, const float* __restrict__ Xv,
    const float* __restrict__ W, const float* __restrict__ Bias,
    f16* __restrict__ Qo, f16* __restrict__ Ko, f16* __restrict__ Vo)
{
    // swizzle: xcd = flat&7; 48 groups (m,proj) per XCD; 4 f-tiles per group
    const int flat = blockIdx.x;
    const int xcd  = flat & 7;
    const int slot = flat >> 3;            // 0..191
    const int g    = xcd * 48 + (slot >> 2);   // 0..383 = proj*128 + mtile
    const int f0   = (slot & 3) << 7;
    const int proj = g >> 7;               // 0=q 1=k 2=v
    const int n0   = (g & 127) << 7;

    const float* X  = (proj == 0) ? Xq : (proj == 1) ? Xk : Xv;
    const float* Wp = W + (size_t)(proj << 9) * E_DIM;

    // f16 tiles, padded rows (40 f16 = 80 B -> bank spread), double-buffered. 40 KB.
    __shared__ __align__(16) f16 As[2][128][40];
    __shared__ __align__(16) f16 Bs[2][128][40];

    const int tid  = threadIdx.x;
    const int w    = tid >> 6;
    const int lane = tid & 63;
    const int quad = lane >> 4, c = lane & 15;
    const int wm = (w >> 1) << 6, wn = (w & 1) << 6;

    // staging: wave w covers rows [w*32, w*32+32); instr i: row = w*32+i*8+(lane>>3),
    // cols (lane&7)*4 .. +3 (fp32) -> 8 rows x 128 B contiguous segments per instr.
    const int srow = (w << 5) + (lane >> 3);     // + i*8
    const int scol = (lane & 7) << 2;
    const float* Xg = X  + (size_t)(n0 + srow) * E_DIM + scol;
    const float* Wg = Wp + (size_t)(f0 + srow) * E_DIM + scol;

    float4 lx[4], lw[4];
    auto load_tile = [&](int kk) {
#pragma unroll
        for (int i = 0; i < 4; ++i)
            lx[i] = *reinterpret_cast<const float4*>(Xg + (size_t)(i * 8) * E_DIM + kk);
#pragma unroll
        for (int i = 0; i < 4; ++i)
            lw[i] = *reinterpret_cast<const float4*>(Wg + (size_t)(i * 8) * E_DIM + kk);
    };
    auto write_tile = [&](int buf) {
#pragma unroll
        for (int i = 0; i < 4; ++i)
            *reinterpret_cast<half4*>(&As[buf][srow + i * 8][scol]) = cvt4(lx[i]);
#pragma unroll
        for (int i = 0; i < 4; ++i)
            *reinterpret_cast<half4*>(&Bs[buf][srow + i * 8][scol]) = cvt4(lw[i]);
    };

    floatx4 acc[4][4] = {};

    // prologue: tile0 staged+visible; tile1 loads in flight
    load_tile(0);
    write_tile(0);
    load_tile(32);
    LGKM_BARRIER();

    for (int t = 0; t < 16; ++t) {
        const int cur = t & 1;

        half8 a[4], bfr[4];
#pragma unroll
        for (int mt = 0; mt < 4; ++mt)
            a[mt] = *reinterpret_cast<const half8*>(&As[cur][wm + mt * 16 + c][quad * 8]);
#pragma unroll
        for (int nt = 0; nt < 4; ++nt)
            bfr[nt] = *reinterpret_cast<const half8*>(&Bs[cur][wn + nt * 16 + c][quad * 8]);
#pragma unroll
        for (int mt = 0; mt < 4; ++mt)
#pragma unroll
            for (int nt = 0; nt < 4; ++nt)
                acc[mt][nt] = __builtin_amdgcn_mfma_f32_16x16x32_f16(a[mt], bfr[nt], acc[mt][nt], 0, 0, 0);

        if (t < 15) {
            write_tile(cur ^ 1);               // cvt consumes loads(t+1); auto vmcnt wait
            if (t < 14) load_tile((t + 2) * 32);  // regs free -> issue next, flies over barrier
        }
        LGKM_BARRIER();
    }

    f16* Dst = (proj == 0) ? Qo : (proj == 1) ? Ko : Vo;
    // q pre-scale folds softmax base-change: exp(x) = exp2(x*log2e)
    const float scale = (proj == 0) ? (0.125f * LOG2E) : 1.0f;

#pragma unroll
    for (int nt = 0; nt < 4; ++nt) {
        const int fl = f0 + wn + nt * 16 + c;
        const float bj = Bias[(proj << 9) + fl];
        const int h = fl >> 6, d = fl & 63;
#pragma unroll
        for (int mt = 0; mt < 4; ++mt) {
#pragma unroll
            for (int r = 0; r < 4; ++r) {
                const int n = n0 + wm + mt * 16 + quad * 4 + r;
                const int l = n >> 4, b = n & 15;
                Dst[((((size_t)b * H_N + h) * L_SEQ + l) << 6) + d] =
                    (f16)((acc[mt][nt][r] + bj) * scale);
            }
        }
    }
}

// ---------------------------------------------------------------------------
// Stage 2: V (b,h)[l][d] -> Vt (b,h)[d][l]. grid (16, 128), block 256.
// ---------------------------------------------------------------------------
__global__ __launch_bounds__(256) void transpose_v(
    const f16* __restrict__ V, f16* __restrict__ Vt)
{
    const int l0 = blockIdx.x << 6;
    const size_t base = (size_t)blockIdx.y << 16;
    __shared__ __align__(16) f16 T[64][72];
    const int tid = threadIdx.x;
    const int r = tid >> 2, co = (tid & 3) << 4;

    const uint4 a0 = *reinterpret_cast<const uint4*>(V + base + (size_t)(l0 + r) * 64 + co);
    const uint4 a1 = *reinterpret_cast<const uint4*>(V + base + (size_t)(l0 + r) * 64 + co + 8);
    *reinterpret_cast<uint4*>(&T[r][co])     = a0;
    *reinterpret_cast<uint4*>(&T[r][co + 8]) = a1;
    __syncthreads();

    union { f16 h[16]; uint4 u[2]; } pk;
#pragma unroll
    for (int j = 0; j < 16; ++j) pk.h[j] = T[co + j][r];
    *reinterpret_cast<uint4*>(Vt + base + (size_t)r * 1024 + l0 + co)     = pk.u[0];
    *reinterpret_cast<uint4*>(Vt + base + (size_t)r * 1024 + l0 + co + 8) = pk.u[1];
}

// ---------------------------------------------------------------------------
// Stage 3: MFMA flash attention, fixed-max softmax. 1024 blocks, block 256.
// R15: R10 body (idx loads in-loop: their vmcnt dependency fences the conflicted
// tab gathers behind QK^T, keeping the MFMA burst clean) + hardware exp2
// (tab pre-scaled log2e; Q pre-scaled in qkv).
// XCD swizzle: the 8 q-tile blocks of each (b,h) share K/V through one L2.
// ---------------------------------------------------------------------------
__global__ __launch_bounds__(256, 3) void attn_kernel(
    const f16* __restrict__ Q, const f16* __restrict__ K, const f16* __restrict__ Vt,
    const int* __restrict__ RPE, const float* __restrict__ Tab, f16* __restrict__ CTX)
{
    // swizzle: xcd = flat&7; bh = (slot>>3)*8 + xcd; q-tile = slot&7
    const int flat = blockIdx.x;
    const int xcd  = flat & 7;
    const int slot = flat >> 3;            // 0..127
    const int q0   = (slot & 7) << 7;
    const int bh   = ((slot >> 3) << 3) + xcd;
    const int b = bh >> 3, h = bh & 7;

    const int tid  = threadIdx.x;
    const int w    = tid >> 6;
    const int lane = tid & 63;
    const int quad = lane >> 4, c = lane & 15;

    __shared__ __align__(16) f16 Ks[64][72];
    __shared__ __align__(16) f16 Vts[64][72];
    __shared__ __align__(16) f16 Pw[4][32][72];
    __shared__ float tab[NREL];

    const size_t base = (size_t)bh << 16;

    // tab pre-scaled by log2e: exp(s+t) == exp2(s*log2e + t*log2e)
    for (int i = tid; i < NREL; i += 256) tab[i] = Tab[h * NREL + i] * LOG2E;

    const int qg0 = q0 + (w << 5);
    half8 Aq[2][2];
#pragma unroll
    for (int s = 0; s < 2; ++s) {
        const f16* qp = Q + base + (size_t)(qg0 + s * 16 + c) * 64 + quad * 8;
        Aq[s][0] = *reinterpret_cast<const half8*>(qp);
        Aq[s][1] = *reinterpret_cast<const half8*>(qp + 32);
    }

    floatx4 o[2][4] = {};
    float l_part[2][4] = {};

    const int* rp = RPE + (size_t)(qg0 + (quad << 2)) * 1024 + c;

    const int sr = tid >> 2, so = (tid & 3) << 4;
    const f16* kbase = K  + base + (size_t)sr * 64 + so;
    const f16* vbase = Vt + base + (size_t)sr * 1024 + so;

    uint4 pk0 = *reinterpret_cast<const uint4*>(kbase);
    uint4 pk1 = *reinterpret_cast<const uint4*>(kbase + 8);
    uint4 pv0 = *reinterpret_cast<const uint4*>(vbase);
    uint4 pv1 = *reinterpret_cast<const uint4*>(vbase + 8);

    for (int j0 = 0; j0 < L_SEQ; j0 += 64) {
        __syncthreads();
        *reinterpret_cast<uint4*>(&Ks[sr][so])      = pk0;
        *reinterpret_cast<uint4*>(&Ks[sr][so + 8])  = pk1;
        *reinterpret_cast<uint4*>(&Vts[sr][so])     = pv0;
        *reinterpret_cast<uint4*>(&Vts[sr][so + 8]) = pv1;
        __syncthreads();

        if (j0 + 64 < L_SEQ) {
            const f16* kn = kbase + (size_t)(j0 + 64) * 64;
            const f16* vn = vbase + (j0 + 64);
            pk0 = *reinterpret_cast<const uint4*>(kn);
            pk1 = *reinterpret_cast<const uint4*>(kn + 8);
            pv0 = *reinterpret_cast<const uint4*>(vn);
            pv1 = *reinterpret_cast<const uint4*>(vn + 8);
        }

        // idx loads in-loop (R10 position): consumed by this iteration's exp.
        // Their vmcnt wait keeps the tab gathers out of the QK^T MFMA shadow.
        int idx[2][4][4];
#pragma unroll
        for (int s = 0; s < 2; ++s)
#pragma unroll
            for (int r = 0; r < 4; ++r)
#pragma unroll
                for (int nt = 0; nt < 4; ++nt)
                    idx[s][r][nt] = rp[(size_t)(s * 16 + r) * 1024 + j0 + nt * 16];

        floatx4 sc[2][4];
#pragma unroll
        for (int nt = 0; nt < 4; ++nt) {
            const half8 b0 = *reinterpret_cast<const half8*>(&Ks[nt * 16 + c][quad * 8]);
            const half8 b1 = *reinterpret_cast<const half8*>(&Ks[nt * 16 + c][32 + quad * 8]);
            floatx4 t0 = {}, t1 = {};
            t0 = __builtin_amdgcn_mfma_f32_16x16x32_f16(Aq[0][0], b0, t0, 0, 0, 0);
            t0 = __builtin_amdgcn_mfma_f32_16x16x32_f16(Aq[0][1], b1, t0, 0, 0, 0);
            t1 = __builtin_amdgcn_mfma_f32_16x16x32_f16(Aq[1][0], b0, t1, 0, 0, 0);
            t1 = __builtin_amdgcn_mfma_f32_16x16x32_f16(Aq[1][1], b1, t1, 0, 0, 0);
            sc[0][nt] = t0; sc[1][nt] = t1;
        }

#pragma unroll
        for (int s = 0; s < 2; ++s)
#pragma unroll
            for (int r = 0; r < 4; ++r) {
                float rs = 0.0f;
#pragma unroll
                for (int nt = 0; nt < 4; ++nt) {
                    const float p = fast_exp2(sc[s][nt][r] + tab[idx[s][r][nt]]);
                    rs += p;
                    Pw[w][s * 16 + quad * 4 + r][nt * 16 + c] = (f16)p;
                }
                l_part[s][r] += rs;
            }

        half8 vb[4][2];
#pragma unroll
        for (int nt = 0; nt < 4; ++nt) {
            vb[nt][0] = *reinterpret_cast<const half8*>(&Vts[nt * 16 + c][quad * 8]);
            vb[nt][1] = *reinterpret_cast<const half8*>(&Vts[nt * 16 + c][32 + quad * 8]);
        }
#pragma unroll
        for (int s = 0; s < 2; ++s) {
            const half8 Ap0 = *reinterpret_cast<const half8*>(&Pw[w][s * 16 + c][quad * 8]);
            const half8 Ap1 = *reinterpret_cast<const half8*>(&Pw[w][s * 16 + c][32 + quad * 8]);
#pragma unroll
            for (int nt = 0; nt < 4; ++nt) {
                o[s][nt] = __builtin_amdgcn_mfma_f32_16x16x32_f16(Ap0, vb[nt][0], o[s][nt], 0, 0, 0);
                o[s][nt] = __builtin_amdgcn_mfma_f32_16x16x32_f16(Ap1, vb[nt][1], o[s][nt], 0, 0, 0);
            }
        }
    }

#pragma unroll
    for (int s = 0; s < 2; ++s)
#pragma unroll
        for (int r = 0; r < 4; ++r) {
            float l = l_part[s][r];
            l += __shfl_xor(l, 1); l += __shfl_xor(l, 2);
            l += __shfl_xor(l, 4); l += __shfl_xor(l, 8);
            const float inv = 1.0f / l;
            const int lrow = qg0 + s * 16 + quad * 4 + r;
            f16* dp = CTX + ((size_t)(lrow * 16 + b)) * 512 + h * 64;
#pragma unroll
            for (int nt = 0; nt < 4; ++nt)
                dp[nt * 16 + c] = (f16)(o[s][nt][r] * inv);
        }
}

// ---------------------------------------------------------------------------
// Stage 4: out_proj MFMA GEMM. 512 blocks, XCD-swizzled, R10 pipeline.
// A = CTX (f16 pass-through regs); B = W (fp32 -> cvt at write).
// ---------------------------------------------------------------------------
__global__ __launch_bounds__(256) void out_kernel(
    const f16* __restrict__ X, const float* __restrict__ W, const float* __restrict__ Bias,
    float* __restrict__ Out)
{
    // swizzle: 16 m-groups per XCD, 4 f-tiles per group on same XCD
    const int flat = blockIdx.x;
    const int xcd  = flat & 7;
    const int slot = flat >> 3;            // 0..63
    const int m    = xcd * 16 + (slot >> 2);   // 0..127
    const int f0   = (slot & 3) << 7;
    const int n0   = m << 7;

    __shared__ __align__(16) f16 As[2][128][40];
    __shared__ __align__(16) f16 Bs[2][128][40];

    const int tid  = threadIdx.x;
    const int w    = tid >> 6;
    const int lane = tid & 63;
    const int quad = lane >> 4, c = lane & 15;
    const int wm = (w >> 1) << 6, wn = (w & 1) << 6;

    // A staging (f16): instr i: row = w*32 + i*16 + (lane>>2), col = (lane&3)*8
    const int arow = (w << 5) + (lane >> 2);     // + i*16
    const int acol = (lane & 3) << 3;
    const f16* Xg = X + (size_t)(n0 + arow) * E_DIM + acol;

    // B staging (fp32): as qkv
    const int srow = (w << 5) + (lane >> 3);     // + i*8
    const int scol = (lane & 7) << 2;
    const float* Wg = W + (size_t)(f0 + srow) * E_DIM + scol;

    uint4  la[2];
    float4 lw[4];
    auto load_tile = [&](int kk) {
#pragma unroll
        for (int i = 0; i < 2; ++i)
            la[i] = *reinterpret_cast<const uint4*>(Xg + (size_t)(i * 16) * E_DIM + kk);
#pragma unroll
        for (int i = 0; i < 4; ++i)
            lw[i] = *reinterpret_cast<const float4*>(Wg + (size_t)(i * 8) * E_DIM + kk);
    };
    auto write_tile = [&](int buf) {
#pragma unroll
        for (int i = 0; i < 2; ++i)
            *reinterpret_cast<uint4*>(&As[buf][arow + i * 16][acol]) = la[i];
#pragma unroll
        for (int i = 0; i < 4; ++i)
            *reinterpret_cast<half4*>(&Bs[buf][srow + i * 8][scol]) = cvt4(lw[i]);
    };

    floatx4 acc[4][4] = {};

    load_tile(0);
    write_tile(0);
    load_tile(32);
    LGKM_BARRIER();

    for (int t = 0; t < 16; ++t) {
        const int cur = t & 1;

        half8 a[4], bfr[4];
#pragma unroll
        for (int mt = 0; mt < 4; ++mt)
            a[mt] = *reinterpret_cast<const half8*>(&As[cur][wm + mt * 16 + c][quad * 8]);
#pragma unroll
        for (int nt = 0; nt < 4; ++nt)
            bfr[nt] = *reinterpret_cast<const half8*>(&Bs[cur][wn + nt * 16 + c][quad * 8]);
#pragma unroll
        for (int mt = 0; mt < 4; ++mt)
#pragma unroll
            for (int nt = 0; nt < 4; ++nt)
                acc[mt][nt] = __builtin_amdgcn_mfma_f32_16x16x32_f16(a[mt], bfr[nt], acc[mt][nt], 0, 0, 0);

        if (t < 15) {
            write_tile(cur ^ 1);
            if (t < 14) load_tile((t + 2) * 32);
        }
        LGKM_BARRIER();
    }

#pragma unroll
    for (int nt = 0; nt < 4; ++nt) {
        const int f = f0 + wn + nt * 16 + c;
        const float bj = Bias[f];
#pragma unroll
        for (int mt = 0; mt < 4; ++mt) {
#pragma unroll
            for (int r = 0; r < 4; ++r) {
                const int n = n0 + wm + mt * 16 + quad * 4 + r;
                Out[(size_t)n * E_DIM + f] = acc[mt][nt][r] + bj;
            }
        }
    }
}

// ---------------------------------------------------------------------------
extern "C" void kernel_launch(void* const* d_in, const int* in_sizes, int n_in,
                              void* d_out, int out_size, void* d_ws, size_t ws_size,
                              hipStream_t stream) {
    const float* q_in = (const float*)d_in[0];
    const float* k_in = (const float*)d_in[1];
    const float* v_in = (const float*)d_in[2];
    const float* ipw  = (const float*)d_in[3];
    const float* ipb  = (const float*)d_in[4];
    const float* opw  = (const float*)d_in[5];
    const float* opb  = (const float*)d_in[6];
    const float* tab  = (const float*)d_in[7];
    const int*   rpe  = (const int*)d_in[8];
    float* out = (float*)d_out;

    f16* ws   = (f16*)d_ws;
    f16* Q    = ws;
    f16* K    = ws + 8388608;
    f16* Vt   = ws + 16777216;
    f16* Vtmp = ws + 25165824;
    f16* CTX  = ws + 25165824;

    qkv_kernel<<<dim3(1536), 256, 0, stream>>>(q_in, k_in, v_in, ipw, ipb, Q, K, Vtmp);
    transpose_v<<<dim3(16, 128), 256, 0, stream>>>(Vtmp, Vt);
    attn_kernel<<<dim3(1024), 256, 0, stream>>>(Q, K, Vt, rpe, tab, CTX);
    out_kernel<<<dim3(512), 256, 0, stream>>>(CTX, opw, opb, out);
}